// Round 7
// baseline (40.859 us; speedup 1.0000x reference)
//
#include <hip/hip_runtime.h>
#include <hip/hip_bf16.h>
#include <stdint.h>

// MultiDense: out[b,s,:] = values[b,s,:] @ W[lookups[b]] + bias[lookups[b]]
// B=16384, S=4, IN=OUT=128, 64 experts.
//
// R7: compaction without atomics. (R5->R6 proved atomic contention was ~24us;
// the remaining solo-block LDS-atomic histogram ~16384 serialized ops is the
// residual suspect.) Block 64 of prep now uses ballot multi-split:
//   per t-step, 6 __ballots -> equal-expert lane mask -> rank & count in-reg;
//   per-wave private LDS hist row updated by one leader ds_write (no atomics,
//   no cross-wave contention); then barrier + 64-thread cross-wave prefix +
//   barrier + scatter. Gemm unchanged from R6 (isolate the variable).

#define NDIMS   64
#define IN_DIM  128
#define OUT_DIM 128
#define BATCH   16384
#define SEQ     4
#define LISTCAP 2048

// d_ws layout (bytes):
//   [0, 256)          cnt[64] (int32, plain-stored by prep each call)
//   [4096, 266240)    lists: 64 x LISTCAP x uint16
//   [524288, 2621440) W bf16 fragment layout: 64 x 8192 x ushort
#define WS_LISTS_OFF  4096
#define WS_WBF16_OFF  524288

using bf16x8 = __attribute__((ext_vector_type(8))) __bf16;
using f32x4  = __attribute__((ext_vector_type(4))) float;

static __device__ inline uint16_t bf16bits(float f) {
    __bf16 h = (__bf16)f;                   // RNE convert
    return __builtin_bit_cast(uint16_t, h);
}

static __device__ inline bf16x8 cvt8(f32x4 v0, f32x4 v1) {
    bf16x8 r;
    r[0] = (__bf16)v0[0]; r[1] = (__bf16)v0[1];
    r[2] = (__bf16)v0[2]; r[3] = (__bf16)v0[3];
    r[4] = (__bf16)v1[0]; r[5] = (__bf16)v1[1];
    r[6] = (__bf16)v1[2]; r[7] = (__bf16)v1[3];
    return r;
}

// ---- K1: prep. blocks 0..63 convert W; block 64 compacts lookups. ----
__global__ __launch_bounds__(1024)
void prep_kernel(const float* __restrict__ W,
                 const int*   __restrict__ lookups,
                 int*            cnt,
                 unsigned short* lists,
                 unsigned short* wsW)
{
    const int tid = threadIdx.x;

    if (blockIdx.x < 64) {
        // convert expert e: chunk = (((nf*4+ks)*16+l15)*4+l4); 8 bf16/chunk:
        // wo[chunk*8+j] = W[k0+j][o], o = nf*16+l15, k0 = ks*32+l4*8.
        const int e = blockIdx.x;
        const float* We = W + (size_t)e * (IN_DIM * OUT_DIM);
        unsigned short* wo = wsW + (size_t)e * (IN_DIM * OUT_DIM);
        #pragma unroll
        for (int it = 0; it < 2; ++it) {
            int chunk = it * 1024 + tid;          // 0..2047
            int l4  = chunk & 3;
            int l15 = (chunk >> 2) & 15;
            int ks  = (chunk >> 6) & 3;
            int nf  = chunk >> 8;
            int o   = nf * 16 + l15;
            int k0  = ks * 32 + l4 * 8;
            unsigned short r[8];
            #pragma unroll
            for (int j = 0; j < 8; ++j)
                r[j] = bf16bits(We[(k0 + j) * OUT_DIM + o]);
            *(uint64_t*)(wo + chunk * 8)     = *(const uint64_t*)&r[0];
            *(uint64_t*)(wo + chunk * 8 + 4) = *(const uint64_t*)&r[4];
        }
    } else {
        // solo compaction of all 16384 lookups; NO atomics (ballot multi-split).
        __shared__ int lh[16 * NDIMS];    // per-wave running hist
        __shared__ int loff[16 * NDIMS];  // cross-wave exclusive offsets

        const int lane = tid & 63;
        const int w    = tid >> 6;
        const uint64_t ltmask = (lane == 63) ? ~0ull >> 1
                                             : ((1ull << lane) - 1);

        lh[tid] = 0;   // each wave zeroes its own row (in-wave ordering suffices)

        int ev[16], pv[16];
        #pragma unroll
        for (int t = 0; t < 16; ++t)
            ev[t] = lookups[t * 1024 + tid];

        #pragma unroll
        for (int t = 0; t < 16; ++t) {
            const int e = ev[t];
            // mask of lanes in this wave holding the same expert
            uint64_t meq = ~0ull;
            #pragma unroll
            for (int b = 0; b < 6; ++b) {
                uint64_t v = __ballot((e >> b) & 1);
                meq &= ((e >> b) & 1) ? v : ~v;
            }
            int rank = __popcll(meq & ltmask);       // my rank among equals
            int cnt_i = __popcll(meq);               // equals in this step
            int base  = lh[w * NDIMS + e];           // per-wave running count
            pv[t] = base + rank;
            if (rank == 0)                           // leader bumps the counter
                lh[w * NDIMS + e] = base + cnt_i;
        }

        __syncthreads();

        // cross-wave exclusive prefix per expert + global cnt store
        if (tid < NDIMS) {
            int run = 0;
            #pragma unroll
            for (int ww = 0; ww < 16; ++ww) {
                loff[ww * NDIMS + tid] = run;
                run += lh[ww * NDIMS + tid];
            }
            cnt[tid] = run < LISTCAP ? run : LISTCAP;
        }

        __syncthreads();

        #pragma unroll
        for (int t = 0; t < 16; ++t) {
            int e   = ev[t];
            int pos = loff[w * NDIMS + e] + pv[t];
            if (pos < LISTCAP)
                lists[e * LISTCAP + pos] = (unsigned short)(t * 1024 + tid);
        }
    }
}

// ---- K2: gemm. One 4-sample group per wave; whole problem resident. ----
__global__ __launch_bounds__(256, 4)
void gemm_kernel(const float* __restrict__ values,
                 const float* __restrict__ bias,
                 const int*   __restrict__ cnt,
                 const unsigned short* __restrict__ lists,
                 const unsigned short* __restrict__ wsW,
                 float*       __restrict__ out)
{
    const int lane = threadIdx.x & 63;
    const int wid  = threadIdx.x >> 6;
    const int l15  = lane & 15;
    const int l4   = lane >> 4;

    // wave-wide exclusive prefix over per-expert group counts (lane = expert)
    int cl   = cnt[lane];
    int grpl = (cl + 3) >> 2;
    int pfx  = grpl;
    #pragma unroll
    for (int d = 1; d < 64; d <<= 1) {
        int t = __shfl_up(pfx, d);
        if (lane >= d) pfx += t;
    }
    const int G    = __shfl(pfx, 63);
    const int excl = pfx - grpl;

    const int nwaves = gridDim.x << 2;
    for (int g = (blockIdx.x << 2) + wid; g < G; g += nwaves) {
        // owning expert: highest lane with excl <= g
        uint64_t m = __ballot(excl <= g);
        int e  = 63 - __builtin_clzll(m);
        int go = g - __shfl(excl, e);
        int ce = __shfl(cl, e);

        // A fragment: row = l15 -> sample go*4+(l15>>2), seq row l15&3
        int pos = go * 4 + (l15 >> 2);
        pos = pos < ce ? pos : ce - 1;                 // clamp tail (stores masked)
        int b = (int)lists[e * LISTCAP + pos];
        const float* pA = values + (size_t)(b * SEQ + (l15 & 3)) * IN_DIM + l4 * 8;

        // B fragment base for this lane
        const unsigned short* wb = wsW + (size_t)e * (IN_DIM * OUT_DIM) + (l15 * 4 + l4) * 8;

        f32x4 acc[8];
        #pragma unroll
        for (int nf = 0; nf < 8; ++nf) {
            float bv = bias[e * OUT_DIM + nf * 16 + l15];
            f32x4 a; a[0] = bv; a[1] = bv; a[2] = bv; a[3] = bv;
            acc[nf] = a;
        }

        #pragma unroll
        for (int ks = 0; ks < 4; ++ks) {
            f32x4 v0 = *(const f32x4*)(pA + ks * 32);
            f32x4 v1 = *(const f32x4*)(pA + ks * 32 + 4);
            bf16x8 afr = cvt8(v0, v1);
            #pragma unroll
            for (int nf = 0; nf < 8; ++nf) {
                const bf16x8 bfr = *(const bf16x8*)(wb + (nf * 4 + ks) * 512);
                acc[nf] = __builtin_amdgcn_mfma_f32_16x16x32_bf16(afr, bfr, acc[nf], 0, 0, 0);
            }
        }

        // store: D layout col = l15, row = l4*4 + r (row -> sample go*4+(row>>2))
        #pragma unroll
        for (int r = 0; r < 4; ++r) {
            int row  = l4 * 4 + r;
            int pos2 = go * 4 + (row >> 2);
            if (pos2 < ce) {
                int b2 = (int)lists[e * LISTCAP + pos2];
                float* po = out + (size_t)(b2 * SEQ + (row & 3)) * OUT_DIM + l15;
                #pragma unroll
                for (int nf = 0; nf < 8; ++nf) po[nf * 16] = acc[nf][r];
            }
        }
    }
}

extern "C" void kernel_launch(void* const* d_in, const int* in_sizes, int n_in,
                              void* d_out, int out_size, void* d_ws, size_t ws_size,
                              hipStream_t stream) {
    const float* values  = (const float*)d_in[0];
    const float* W       = (const float*)d_in[1];
    const float* bias    = (const float*)d_in[2];
    const int*   lookups = (const int*)d_in[3];
    float* out = (float*)d_out;

    int*            cnt   = (int*)d_ws;
    unsigned short* lists = (unsigned short*)((char*)d_ws + WS_LISTS_OFF);
    unsigned short* wsW   = (unsigned short*)((char*)d_ws + WS_WBF16_OFF);

    hipLaunchKernelGGL(prep_kernel, dim3(65), dim3(1024), 0, stream,
                       W, lookups, cnt, lists, wsW);
    hipLaunchKernelGGL(gemm_kernel, dim3(1024), dim3(256), 0, stream,
                       values, bias, cnt, lists, wsW, out);
}